// Round 16
// baseline (824.015 us; speedup 1.0000x reference)
//
#include <hip/hip_runtime.h>

#define EXPERTS 8
#define HID 2048
#define INTER 4096
#define BTOK 2048
#define NASSIGN 4096   // BTOK * TOPK
#define NTSLOTS 40     // max sum_e ceil(cnt_e/128) = 32+7

typedef float f32x4 __attribute__((ext_vector_type(4)));
typedef __bf16 bf16x8 __attribute__((ext_vector_type(8)));
typedef unsigned short ushortx8 __attribute__((ext_vector_type(8)));

__device__ __forceinline__ unsigned short f2bf(float f) {
  union { float f; unsigned int u; } v; v.f = f;
  unsigned int r = v.u + 0x7fffu + ((v.u >> 16) & 1u);   // RNE
  return (unsigned short)(r >> 16);
}

// ---------------- workspace layout (bytes) ----------------
#define XB_OFF   0ULL                                   // [BTOK][HID] bf16 = 8 MiB
#define GB_OFF   (XB_OFF + 8388608ULL)                  // [NASSIGN][INTER] bf16 = 32 MiB
#define Y_OFF    (GB_OFF + 33554432ULL)                 // [NASSIGN][HID] f32 = 32 MiB
#define ROWS_OFF (Y_OFF  + 33554432ULL)                 // 4096 int
#define OFFS_OFF (ROWS_OFF + 16384ULL)                  // 9 int (padded 64B)
#define TILE_OFF (OFFS_OFF + 64ULL)                     // 40 int

// ---------------- prep: routing (block 0) + x f32->bf16 ----------------
__global__ void prep_kernel(const int* __restrict__ eraw,
                            const float* __restrict__ x,
                            unsigned short* __restrict__ xb,
                            int* __restrict__ rows, int* __restrict__ offs_g,
                            int* __restrict__ tiles)
{
  const int b = blockIdx.x;
  const int tid = threadIdx.x;

  if (b == 0) {
    __shared__ int cnt[256 * 8];
    __shared__ int offs_s[9];
    __shared__ int tot[8];
    __shared__ int found_odd;
    if (tid == 0) found_odd = 0;
    __syncthreads();
    int any = 0;
    for (int j = 0; j < 8; ++j) {
      int a = tid * 8 + j;
      any |= (eraw[2 * a + 1] != 0);
    }
    if (any) atomicOr(&found_odd, 1);
    __syncthreads();
    const bool i64 = (found_odd == 0);
    int lc[8];
    for (int e = 0; e < 8; ++e) lc[e] = 0;
    for (int j = 0; j < 16; ++j) {
      int a = tid * 16 + j;
      int e = i64 ? eraw[2 * a] : eraw[a];
      lc[e]++;
    }
    for (int e = 0; e < 8; ++e) cnt[tid * 8 + e] = lc[e];
    __syncthreads();
    if (tid < 8) {
      int run = 0;
      for (int t = 0; t < 256; ++t) {
        int v = cnt[t * 8 + tid];
        cnt[t * 8 + tid] = run;
        run += v;
      }
      tot[tid] = run;
    }
    __syncthreads();
    if (tid == 0) {
      int o = 0;
      for (int e = 0; e < 8; ++e) { offs_s[e] = o; o += tot[e]; }
      offs_s[8] = o;
      int s = 0;
      for (int e = 0; e < 8; ++e) {
        int nmt = (tot[e] + 127) >> 7;
        for (int m = 0; m < nmt; ++m) tiles[s++] = (e << 16) | m;
      }
      for (; s < NTSLOTS; ++s) tiles[s] = -1;
    }
    __syncthreads();
    if (tid < 9) offs_g[tid] = offs_s[tid];
    int lc2[8];
    for (int e = 0; e < 8; ++e) lc2[e] = 0;
    for (int j = 0; j < 16; ++j) {
      int a = tid * 16 + j;
      int e = i64 ? eraw[2 * a] : eraw[a];
      rows[offs_s[e] + cnt[tid * 8 + e] + lc2[e]] = a;
      lc2[e]++;
    }
  } else {
    long idx = (long)(b - 1) * 256 + tid;
    float4 v = *(const float4*)&x[idx * 4];
    unsigned int lo = (unsigned int)f2bf(v.x) | ((unsigned int)f2bf(v.y) << 16);
    unsigned int hi = (unsigned int)f2bf(v.z) | ((unsigned int)f2bf(v.w) << 16);
    uint2 p; p.x = lo; p.y = hi;
    *(uint2*)&xb[idx * 4] = p;
  }
}

// ---------------- gate+up grouped GEMM, direct fp32, mixed-depth pipeline ---
// B fp32 tiles depth-2 double-buffered (counted vmcnt, never drain-to-0 in
// steady state); A bf16 depth-1. Per iter:
//   vmcnt(6)[B(t) done] -> bar -> convert(t) ->
//   vmcnt(4)[A(t) done] + lgkmcnt(0)[Bbf ds_writes committed] -> bar
//   -> STAGE_A(t+1)+STAGE_B(t+2) -> MFMA(t)
// The lgkmcnt(0) is the R15 bugfix: raw s_barrier does NOT drain LDS writes;
// Bbf is produced by ds_write and consumed cross-wave after the barrier.
__global__ __launch_bounds__(256, 2) void gemm_gateup(
    const unsigned short* __restrict__ xb,
    const float* __restrict__ w1,
    const float* __restrict__ w3,
    unsigned short* __restrict__ gb,
    const int* __restrict__ rows,
    const int* __restrict__ offs,
    const int* __restrict__ tiles)
{
  const int te = tiles[blockIdx.y];
  if (te < 0) return;
  const int e  = te >> 16, mt = te & 0xffff;
  const int off = offs[e];
  const int cnt = offs[e + 1] - off;
  const int nt  = blockIdx.x;                 // 64 N-tiles of 64 over INTER

  __shared__ __align__(16) unsigned short As[2][128 * 32];   // 16 KiB
  __shared__ __align__(16) float B1raw[2][32 * 64];          // 16 KiB
  __shared__ __align__(16) float B3raw[2][32 * 64];          // 16 KiB
  __shared__ __align__(16) unsigned short B1bf[4 * 64 * 8];  //  4 KiB
  __shared__ __align__(16) unsigned short B3bf[4 * 64 * 8];  //  4 KiB

  const int tid  = threadIdx.x;
  const int lane = tid & 63;
  const int wave = tid >> 6;
  const int wr = wave >> 1, wc = wave & 1;

  const unsigned short* aptr[2];
  #pragma unroll
  for (int c = 0; c < 2; ++c) {
    int idx = tid + c * 256;
    int row = idx >> 2, seg = idx & 3;
    int rr = off + mt * 128 + row;
    int rv = (rr < off + cnt) ? rr : (off + cnt - 1);
    long tok = rows[rv] >> 1;
    aptr[c] = xb + tok * HID + seg * 8;
  }
  const float* b1p[2];
  const float* b3p[2];
  #pragma unroll
  for (int c = 0; c < 2; ++c) {
    int k = (tid >> 4) + c * 16, n4 = (tid & 15) * 4;
    b1p[c] = w1 + ((long)e * HID + k) * INTER + nt * 64 + n4;
    b3p[c] = w3 + ((long)e * HID + k) * INTER + nt * 64 + n4;
  }

  auto STAGE_A = [&](int abuf, long k32) {   // 2 VMEM loads
    #pragma unroll
    for (int c = 0; c < 2; ++c)
      __builtin_amdgcn_global_load_lds(
          (const __attribute__((address_space(1))) unsigned int*)(aptr[c] + k32),
          (__attribute__((address_space(3))) unsigned int*)(&As[abuf][(tid + c * 256) * 8]),
          16, 0, 0);
  };
  auto STAGE_B = [&](int bbuf, long k32) {   // 4 VMEM loads
    #pragma unroll
    for (int c = 0; c < 2; ++c) {
      __builtin_amdgcn_global_load_lds(
          (const __attribute__((address_space(1))) unsigned int*)(b1p[c] + k32 * INTER),
          (__attribute__((address_space(3))) unsigned int*)(&B1raw[bbuf][(tid + c * 256) * 4]),
          16, 0, 0);
      __builtin_amdgcn_global_load_lds(
          (const __attribute__((address_space(1))) unsigned int*)(b3p[c] + k32 * INTER),
          (__attribute__((address_space(3))) unsigned int*)(&B3raw[bbuf][(tid + c * 256) * 4]),
          16, 0, 0);
    }
  };

  f32x4 acc1[4][2], acc3[4][2];
  #pragma unroll
  for (int i = 0; i < 4; ++i)
    #pragma unroll
    for (int j = 0; j < 2; ++j) { acc1[i][j] = (f32x4)0.0f; acc3[i][j] = (f32x4)0.0f; }

  // prologue: queue = [B(0), A(0), B(1)]
  STAGE_B(0, 0);
  STAGE_A(0, 0);
  STAGE_B(1, 32);

  const int NIT = HID / 32;   // 64
  const int cn = tid & 63, ck8 = tid >> 6;
  for (int t = 0; t < NIT; ++t) {
    if (t + 1 < NIT) { asm volatile("s_waitcnt vmcnt(6)" ::: "memory"); }
    else             { asm volatile("s_waitcnt vmcnt(2)" ::: "memory"); }
    __builtin_amdgcn_s_barrier();
    asm volatile("" ::: "memory");
    const int bcur = t & 1;
    // convert-transpose B(t): Braw[k][n] -> Bbf[k8][n][8] (native hw cvt)
    {
      bf16x8 p1, p3;
      #pragma unroll
      for (int j = 0; j < 8; ++j) {
        p1[j] = (__bf16)B1raw[bcur][(ck8 * 8 + j) * 64 + cn];
        p3[j] = (__bf16)B3raw[bcur][(ck8 * 8 + j) * 64 + cn];
      }
      *(bf16x8*)&B1bf[(ck8 * 64 + cn) * 8] = p1;
      *(bf16x8*)&B3bf[(ck8 * 64 + cn) * 8] = p3;
    }
    // lgkmcnt(0): commit Bbf ds_writes before crossing the barrier (bugfix)
    if (t + 1 < NIT) { asm volatile("s_waitcnt vmcnt(4) lgkmcnt(0)" ::: "memory"); }
    else             { asm volatile("s_waitcnt vmcnt(0) lgkmcnt(0)" ::: "memory"); }
    __builtin_amdgcn_s_barrier();
    asm volatile("" ::: "memory");
    if (t + 1 < NIT) STAGE_A((t + 1) & 1, (long)(t + 1) * 32);
    if (t + 2 < NIT) STAGE_B(t & 1, (long)(t + 2) * 32);
    const int cur = t & 1;
    const int k8 = lane >> 4;
    bf16x8 af[4], b1f[2], b3f[2];
    #pragma unroll
    for (int f = 0; f < 4; ++f)
      af[f] = __builtin_bit_cast(bf16x8, *(const ushortx8*)&As[cur][(wr * 64 + f * 16 + (lane & 15)) * 32 + k8 * 8]);
    #pragma unroll
    for (int j = 0; j < 2; ++j) {
      b1f[j] = __builtin_bit_cast(bf16x8, *(const ushortx8*)&B1bf[(k8 * 64 + wc * 32 + j * 16 + (lane & 15)) * 8]);
      b3f[j] = __builtin_bit_cast(bf16x8, *(const ushortx8*)&B3bf[(k8 * 64 + wc * 32 + j * 16 + (lane & 15)) * 8]);
    }
    #pragma unroll
    for (int i = 0; i < 4; ++i)
      #pragma unroll
      for (int j = 0; j < 2; ++j) {
        acc1[i][j] = __builtin_amdgcn_mfma_f32_16x16x32_bf16(af[i], b1f[j], acc1[i][j], 0, 0, 0);
        acc3[i][j] = __builtin_amdgcn_mfma_f32_16x16x32_bf16(af[i], b3f[j], acc3[i][j], 0, 0, 0);
      }
  }

  const int rtop = off + cnt;
  const int grb  = off + mt * 128 + wr * 64;
  const int gcb  = nt * 64 + wc * 32;
  #pragma unroll
  for (int i = 0; i < 4; ++i) {
    #pragma unroll
    for (int j = 0; j < 2; ++j) {
      int gc = gcb + j * 16 + (lane & 15);
      #pragma unroll
      for (int qq = 0; qq < 4; ++qq) {
        int gr = grb + i * 16 + (lane >> 4) * 4 + qq;
        if (gr < rtop) {
          float g = acc1[i][j][qq];
          float u = acc3[i][j][qq];
          float s = g / (1.0f + __expf(-g));
          gb[(long)gr * INTER + gc] = f2bf(s * u);
        }
      }
    }
  }
}

// ---------------- down grouped GEMM, direct fp32 w2, mixed-depth pipeline ---
// Same schedule; STAGE_B = 2 loads -> vmcnt(4)/(2) top, (2)/(0) mid.
__global__ __launch_bounds__(256, 4) void gemm_down(
    const unsigned short* __restrict__ gbin,
    const float* __restrict__ w2,
    float* __restrict__ y,
    const int* __restrict__ rows,
    const int* __restrict__ offs,
    const int* __restrict__ tiles)
{
  const int te = tiles[blockIdx.y];
  if (te < 0) return;
  const int e  = te >> 16, mt = te & 0xffff;
  const int off = offs[e];
  const int cnt = offs[e + 1] - off;
  const int nt  = blockIdx.x;                 // 32 N-tiles of 64 over HID

  __shared__ __align__(16) unsigned short As[2][128 * 32];   // 16 KiB
  __shared__ __align__(16) float Braw[2][32 * 64];           // 16 KiB
  __shared__ __align__(16) unsigned short Bbf[4 * 64 * 8];   //  4 KiB

  const int tid  = threadIdx.x;
  const int lane = tid & 63;
  const int wave = tid >> 6;
  const int wr = wave >> 1, wc = wave & 1;

  const unsigned short* aptr[2];
  #pragma unroll
  for (int c = 0; c < 2; ++c) {
    int idx = tid + c * 256;
    int row = idx >> 2, seg = idx & 3;
    int rr = off + mt * 128 + row;
    int rv = (rr < off + cnt) ? rr : (off + cnt - 1);
    aptr[c] = gbin + (long)rv * INTER + seg * 8;
  }
  const float* bp[2];
  #pragma unroll
  for (int c = 0; c < 2; ++c) {
    int k = (tid >> 4) + c * 16, n4 = (tid & 15) * 4;
    bp[c] = w2 + ((long)e * INTER + k) * HID + nt * 64 + n4;
  }

  auto STAGE_A = [&](int abuf, long k32) {   // 2 VMEM loads
    #pragma unroll
    for (int c = 0; c < 2; ++c)
      __builtin_amdgcn_global_load_lds(
          (const __attribute__((address_space(1))) unsigned int*)(aptr[c] + k32),
          (__attribute__((address_space(3))) unsigned int*)(&As[abuf][(tid + c * 256) * 8]),
          16, 0, 0);
  };
  auto STAGE_B = [&](int bbuf, long k32) {   // 2 VMEM loads
    #pragma unroll
    for (int c = 0; c < 2; ++c)
      __builtin_amdgcn_global_load_lds(
          (const __attribute__((address_space(1))) unsigned int*)(bp[c] + k32 * HID),
          (__attribute__((address_space(3))) unsigned int*)(&Braw[bbuf][(tid + c * 256) * 4]),
          16, 0, 0);
  };

  f32x4 acc[4][2];
  #pragma unroll
  for (int i = 0; i < 4; ++i)
    #pragma unroll
    for (int j = 0; j < 2; ++j) acc[i][j] = (f32x4)0.0f;

  STAGE_B(0, 0);
  STAGE_A(0, 0);
  STAGE_B(1, 32);

  const int NIT = INTER / 32;   // 128
  const int cn = tid & 63, ck8 = tid >> 6;
  for (int t = 0; t < NIT; ++t) {
    if (t + 1 < NIT) { asm volatile("s_waitcnt vmcnt(4)" ::: "memory"); }
    else             { asm volatile("s_waitcnt vmcnt(2)" ::: "memory"); }
    __builtin_amdgcn_s_barrier();
    asm volatile("" ::: "memory");
    const int bcur = t & 1;
    {
      bf16x8 pk;
      #pragma unroll
      for (int j = 0; j < 8; ++j)
        pk[j] = (__bf16)Braw[bcur][(ck8 * 8 + j) * 64 + cn];
      *(bf16x8*)&Bbf[(ck8 * 64 + cn) * 8] = pk;
    }
    // lgkmcnt(0): commit Bbf ds_writes before crossing the barrier (bugfix)
    if (t + 1 < NIT) { asm volatile("s_waitcnt vmcnt(2) lgkmcnt(0)" ::: "memory"); }
    else             { asm volatile("s_waitcnt vmcnt(0) lgkmcnt(0)" ::: "memory"); }
    __builtin_amdgcn_s_barrier();
    asm volatile("" ::: "memory");
    if (t + 1 < NIT) STAGE_A((t + 1) & 1, (long)(t + 1) * 32);
    if (t + 2 < NIT) STAGE_B(t & 1, (long)(t + 2) * 32);
    const int cur = t & 1;
    const int k8 = lane >> 4;
    bf16x8 af[4], bf[2];
    #pragma unroll
    for (int f = 0; f < 4; ++f)
      af[f] = __builtin_bit_cast(bf16x8, *(const ushortx8*)&As[cur][(wr * 64 + f * 16 + (lane & 15)) * 32 + k8 * 8]);
    #pragma unroll
    for (int j = 0; j < 2; ++j)
      bf[j] = __builtin_bit_cast(bf16x8, *(const ushortx8*)&Bbf[(k8 * 64 + wc * 32 + j * 16 + (lane & 15)) * 8]);
    #pragma unroll
    for (int i = 0; i < 4; ++i)
      #pragma unroll
      for (int j = 0; j < 2; ++j)
        acc[i][j] = __builtin_amdgcn_mfma_f32_16x16x32_bf16(af[i], bf[j], acc[i][j], 0, 0, 0);
  }

  const int rtop = off + cnt;
  const int grb  = off + mt * 128 + wr * 64;
  const int gcb  = nt * 64 + wc * 32;
  #pragma unroll
  for (int i = 0; i < 4; ++i) {
    #pragma unroll
    for (int j = 0; j < 2; ++j) {
      int gc = gcb + j * 16 + (lane & 15);
      #pragma unroll
      for (int q = 0; q < 4; ++q) {
        int gr = grb + i * 16 + (lane >> 4) * 4 + q;
        if (gr < rtop) {
          int a = rows[gr];
          y[(long)a * HID + gc] = acc[i][j][q];
        }
      }
    }
  }
}

// ---------------- combine: out[t] = ew0*Y[2t] + ew1*Y[2t+1] ----------------
__global__ void combine_kernel(const float* __restrict__ Y,
                               const float* __restrict__ ew,
                               float* __restrict__ out)
{
  int idx = blockIdx.x * 256 + threadIdx.x;
  int t = idx >> 9;
  int h = (idx & 511) * 4;
  float w0 = ew[2 * t], w1 = ew[2 * t + 1];
  float4 y0 = *(const float4*)&Y[(long)(2 * t) * HID + h];
  float4 y1 = *(const float4*)&Y[(long)(2 * t + 1) * HID + h];
  float4 o;
  o.x = w0 * y0.x + w1 * y1.x;
  o.y = w0 * y0.y + w1 * y1.y;
  o.z = w0 * y0.z + w1 * y1.z;
  o.w = w0 * y0.w + w1 * y1.w;
  *(float4*)&out[(long)t * HID + h] = o;
}

extern "C" void kernel_launch(void* const* d_in, const int* in_sizes, int n_in,
                              void* d_out, int out_size, void* d_ws, size_t ws_size,
                              hipStream_t stream) {
  const float* x   = (const float*)d_in[0];
  const int*   eix = (const int*)d_in[1];
  const float* ew  = (const float*)d_in[2];
  const float* w1  = (const float*)d_in[3];
  const float* w2  = (const float*)d_in[4];
  const float* w3  = (const float*)d_in[5];
  float* out = (float*)d_out;

  char* ws = (char*)d_ws;
  unsigned short* xb  = (unsigned short*)(ws + XB_OFF);
  unsigned short* gb  = (unsigned short*)(ws + GB_OFF);
  float*          y   = (float*)(ws + Y_OFF);
  int*            rows  = (int*)(ws + ROWS_OFF);
  int*            offs  = (int*)(ws + OFFS_OFF);
  int*            tiles = (int*)(ws + TILE_OFF);

  prep_kernel<<<4097, 256, 0, stream>>>(eix, x, xb, rows, offs, tiles);
  gemm_gateup<<<dim3(INTER / 64, NTSLOTS), 256, 0, stream>>>(
      xb, w1, w3, gb, rows, offs, tiles);
  gemm_down<<<dim3(HID / 64, NTSLOTS), 256, 0, stream>>>(
      gb, w2, y, rows, offs, tiles);
  combine_kernel<<<4096, 256, 0, stream>>>(y, ew, out);
}

// Round 18
// 480.759 us; speedup vs baseline: 1.7140x; 1.7140x over previous
//
#include <hip/hip_runtime.h>

#define EXPERTS 8
#define HID 2048
#define INTER 4096
#define BTOK 2048
#define NASSIGN 4096   // BTOK * TOPK
#define NTSLOTS 40     // max sum_e ceil(cnt_e/128) = 32+7

typedef float f32x4 __attribute__((ext_vector_type(4)));
typedef __bf16 bf16x8 __attribute__((ext_vector_type(8)));
typedef unsigned short ushortx8 __attribute__((ext_vector_type(8)));

__device__ __forceinline__ unsigned short f2bf(float f) {
  union { float f; unsigned int u; } v; v.f = f;
  unsigned int r = v.u + 0x7fffu + ((v.u >> 16) & 1u);   // RNE
  return (unsigned short)(r >> 16);
}

// ---------------- workspace layout (bytes) ----------------
#define XB_OFF   0ULL                                   // [BTOK][HID] bf16 = 8 MiB
#define GB_OFF   (XB_OFF + 8388608ULL)                  // [NASSIGN][INTER] bf16 = 32 MiB
#define Y_OFF    (GB_OFF + 33554432ULL)                 // [NASSIGN][HID] f32 = 32 MiB
#define ROWS_OFF (Y_OFF  + 33554432ULL)                 // 4096 int
#define OFFS_OFF (ROWS_OFF + 16384ULL)                  // 9 int (padded 64B)
#define TILE_OFF (OFFS_OFF + 64ULL)                     // 40 int

// ---------------- prep: routing (block 0) + x f32->bf16 ----------------
__global__ void prep_kernel(const int* __restrict__ eraw,
                            const float* __restrict__ x,
                            unsigned short* __restrict__ xb,
                            int* __restrict__ rows, int* __restrict__ offs_g,
                            int* __restrict__ tiles)
{
  const int b = blockIdx.x;
  const int tid = threadIdx.x;

  if (b == 0) {
    __shared__ int cnt[256 * 8];
    __shared__ int offs_s[9];
    __shared__ int tot[8];
    __shared__ int found_odd;
    if (tid == 0) found_odd = 0;
    __syncthreads();
    int any = 0;
    for (int j = 0; j < 8; ++j) {
      int a = tid * 8 + j;
      any |= (eraw[2 * a + 1] != 0);
    }
    if (any) atomicOr(&found_odd, 1);
    __syncthreads();
    const bool i64 = (found_odd == 0);
    int lc[8];
    for (int e = 0; e < 8; ++e) lc[e] = 0;
    for (int j = 0; j < 16; ++j) {
      int a = tid * 16 + j;
      int e = i64 ? eraw[2 * a] : eraw[a];
      lc[e]++;
    }
    for (int e = 0; e < 8; ++e) cnt[tid * 8 + e] = lc[e];
    __syncthreads();
    if (tid < 8) {
      int run = 0;
      for (int t = 0; t < 256; ++t) {
        int v = cnt[t * 8 + tid];
        cnt[t * 8 + tid] = run;
        run += v;
      }
      tot[tid] = run;
    }
    __syncthreads();
    if (tid == 0) {
      int o = 0;
      for (int e = 0; e < 8; ++e) { offs_s[e] = o; o += tot[e]; }
      offs_s[8] = o;
      int s = 0;
      for (int e = 0; e < 8; ++e) {
        int nmt = (tot[e] + 127) >> 7;
        for (int m = 0; m < nmt; ++m) tiles[s++] = (e << 16) | m;
      }
      for (; s < NTSLOTS; ++s) tiles[s] = -1;
    }
    __syncthreads();
    if (tid < 9) offs_g[tid] = offs_s[tid];
    int lc2[8];
    for (int e = 0; e < 8; ++e) lc2[e] = 0;
    for (int j = 0; j < 16; ++j) {
      int a = tid * 16 + j;
      int e = i64 ? eraw[2 * a] : eraw[a];
      rows[offs_s[e] + cnt[tid * 8 + e] + lc2[e]] = a;
      lc2[e]++;
    }
  } else {
    long idx = (long)(b - 1) * 256 + tid;
    float4 v = *(const float4*)&x[idx * 4];
    unsigned int lo = (unsigned int)f2bf(v.x) | ((unsigned int)f2bf(v.y) << 16);
    unsigned int hi = (unsigned int)f2bf(v.z) | ((unsigned int)f2bf(v.w) << 16);
    uint2 p; p.x = lo; p.y = hi;
    *(uint2*)&xb[idx * 4] = p;
  }
}

// ---------------- gate+up grouped GEMM, direct fp32, reg-staged B -----------
// B weights reg-staged (T14): thread owns column-fragment (n=tid&63,
// k8=tid>>6), 8 scalar dword loads (coalesced 256B/wave) that SPAN barriers
// (plain VGPR loads are not drained by __syncthreads). Convert = 8 native
// casts + ONE conflict-free ds_write_b128 into [k8][n][8] (proven read
// layout). ONE barrier per K-iter:
//   convert(t) -> issue rB(t+1) -> sync -> STAGE_A(t+1) -> MFMA(t)
// LDS 32 KiB (As[2] 16K + B1bf[2] 8K + B3bf[2] 8K).
__global__ __launch_bounds__(256, 4) void gemm_gateup(
    const unsigned short* __restrict__ xb,
    const float* __restrict__ w1,
    const float* __restrict__ w3,
    unsigned short* __restrict__ gb,
    const int* __restrict__ rows,
    const int* __restrict__ offs,
    const int* __restrict__ tiles)
{
  const int te = tiles[blockIdx.y];
  if (te < 0) return;
  const int e  = te >> 16, mt = te & 0xffff;
  const int off = offs[e];
  const int cnt = offs[e + 1] - off;
  const int nt  = blockIdx.x;                 // 64 N-tiles of 64 over INTER

  __shared__ __align__(16) unsigned short As[2][128 * 32];    // 16 KiB
  __shared__ __align__(16) unsigned short B1bf[2][4 * 64 * 8];//  8 KiB
  __shared__ __align__(16) unsigned short B3bf[2][4 * 64 * 8];//  8 KiB

  const int tid  = threadIdx.x;
  const int lane = tid & 63;
  const int wave = tid >> 6;
  const int wr = wave >> 1, wc = wave & 1;

  const unsigned short* aptr[2];
  #pragma unroll
  for (int c = 0; c < 2; ++c) {
    int idx = tid + c * 256;
    int row = idx >> 2, seg = idx & 3;
    int rr = off + mt * 128 + row;
    int rv = (rr < off + cnt) ? rr : (off + cnt - 1);
    long tok = rows[rv] >> 1;
    aptr[c] = xb + tok * HID + seg * 8;
  }
  // B reg-staging: thread -> (n = tid&63, k-oct k8 = tid>>6); k = t*32+k8*8+j
  const int bn = tid & 63, bk8 = tid >> 6;
  const float* b1base = w1 + ((long)e * HID + bk8 * 8) * INTER + nt * 64 + bn;
  const float* b3base = w3 + ((long)e * HID + bk8 * 8) * INTER + nt * 64 + bn;

  auto STAGE_A = [&](int abuf, long k32) {
    #pragma unroll
    for (int c = 0; c < 2; ++c)
      __builtin_amdgcn_global_load_lds(
          (const __attribute__((address_space(1))) unsigned int*)(aptr[c] + k32),
          (__attribute__((address_space(3))) unsigned int*)(&As[abuf][(tid + c * 256) * 8]),
          16, 0, 0);
  };

  float rB1[8], rB3[8];
  auto LOAD_B = [&](int t) {
    const float* p1 = b1base + (long)t * 32 * INTER;
    const float* p3 = b3base + (long)t * 32 * INTER;
    #pragma unroll
    for (int j = 0; j < 8; ++j) {
      rB1[j] = p1[(long)j * INTER];
      rB3[j] = p3[(long)j * INTER];
    }
  };

  f32x4 acc1[4][2], acc3[4][2];
  #pragma unroll
  for (int i = 0; i < 4; ++i)
    #pragma unroll
    for (int j = 0; j < 2; ++j) { acc1[i][j] = (f32x4)0.0f; acc3[i][j] = (f32x4)0.0f; }

  LOAD_B(0);
  STAGE_A(0, 0);

  const int NIT = HID / 32;   // 64
  for (int t = 0; t < NIT; ++t) {
    const int p = t & 1;
    // convert B(t) from regs -> Bbf[p] (one b128 write per matrix, banks n*4)
    {
      bf16x8 p1, p3;
      #pragma unroll
      for (int j = 0; j < 8; ++j) {
        p1[j] = (__bf16)rB1[j];
        p3[j] = (__bf16)rB3[j];
      }
      *(bf16x8*)&B1bf[p][(bk8 * 64 + bn) * 8] = p1;
      *(bf16x8*)&B3bf[p][(bk8 * 64 + bn) * 8] = p3;
    }
    if (t + 1 < NIT) LOAD_B(t + 1);          // spans the barrier (VGPR loads)
    __syncthreads();                         // publish Bbf(t); drain As(t)
    if (t + 1 < NIT) STAGE_A((t + 1) & 1, (long)(t + 1) * 32);
    const int k8 = lane >> 4;
    bf16x8 af[4], b1f[2], b3f[2];
    #pragma unroll
    for (int f = 0; f < 4; ++f)
      af[f] = __builtin_bit_cast(bf16x8, *(const ushortx8*)&As[p][(wr * 64 + f * 16 + (lane & 15)) * 32 + k8 * 8]);
    #pragma unroll
    for (int j = 0; j < 2; ++j) {
      b1f[j] = __builtin_bit_cast(bf16x8, *(const ushortx8*)&B1bf[p][(k8 * 64 + wc * 32 + j * 16 + (lane & 15)) * 8]);
      b3f[j] = __builtin_bit_cast(bf16x8, *(const ushortx8*)&B3bf[p][(k8 * 64 + wc * 32 + j * 16 + (lane & 15)) * 8]);
    }
    #pragma unroll
    for (int i = 0; i < 4; ++i)
      #pragma unroll
      for (int j = 0; j < 2; ++j) {
        acc1[i][j] = __builtin_amdgcn_mfma_f32_16x16x32_bf16(af[i], b1f[j], acc1[i][j], 0, 0, 0);
        acc3[i][j] = __builtin_amdgcn_mfma_f32_16x16x32_bf16(af[i], b3f[j], acc3[i][j], 0, 0, 0);
      }
  }

  const int rtop = off + cnt;
  const int grb  = off + mt * 128 + wr * 64;
  const int gcb  = nt * 64 + wc * 32;
  #pragma unroll
  for (int i = 0; i < 4; ++i) {
    #pragma unroll
    for (int j = 0; j < 2; ++j) {
      int gc = gcb + j * 16 + (lane & 15);
      #pragma unroll
      for (int qq = 0; qq < 4; ++qq) {
        int gr = grb + i * 16 + (lane >> 4) * 4 + qq;
        if (gr < rtop) {
          float g = acc1[i][j][qq];
          float u = acc3[i][j][qq];
          float s = g / (1.0f + __expf(-g));
          gb[(long)gr * INTER + gc] = f2bf(s * u);
        }
      }
    }
  }
}

// ---------------- down grouped GEMM, direct fp32 w2, reg-staged B -----------
// Same structure. LDS 24 KiB (As[2] 16K + Bbf[2] 8K).
__global__ __launch_bounds__(256, 4) void gemm_down(
    const unsigned short* __restrict__ gbin,
    const float* __restrict__ w2,
    float* __restrict__ y,
    const int* __restrict__ rows,
    const int* __restrict__ offs,
    const int* __restrict__ tiles)
{
  const int te = tiles[blockIdx.y];
  if (te < 0) return;
  const int e  = te >> 16, mt = te & 0xffff;
  const int off = offs[e];
  const int cnt = offs[e + 1] - off;
  const int nt  = blockIdx.x;                 // 32 N-tiles of 64 over HID

  __shared__ __align__(16) unsigned short As[2][128 * 32];    // 16 KiB
  __shared__ __align__(16) unsigned short Bbf[2][4 * 64 * 8]; //  8 KiB

  const int tid  = threadIdx.x;
  const int lane = tid & 63;
  const int wave = tid >> 6;
  const int wr = wave >> 1, wc = wave & 1;

  const unsigned short* aptr[2];
  #pragma unroll
  for (int c = 0; c < 2; ++c) {
    int idx = tid + c * 256;
    int row = idx >> 2, seg = idx & 3;
    int rr = off + mt * 128 + row;
    int rv = (rr < off + cnt) ? rr : (off + cnt - 1);
    aptr[c] = gbin + (long)rv * INTER + seg * 8;
  }
  const int bn = tid & 63, bk8 = tid >> 6;
  const float* bbase = w2 + ((long)e * INTER + bk8 * 8) * HID + nt * 64 + bn;

  auto STAGE_A = [&](int abuf, long k32) {
    #pragma unroll
    for (int c = 0; c < 2; ++c)
      __builtin_amdgcn_global_load_lds(
          (const __attribute__((address_space(1))) unsigned int*)(aptr[c] + k32),
          (__attribute__((address_space(3))) unsigned int*)(&As[abuf][(tid + c * 256) * 8]),
          16, 0, 0);
  };

  float rB[8];
  auto LOAD_B = [&](int t) {
    const float* p = bbase + (long)t * 32 * HID;
    #pragma unroll
    for (int j = 0; j < 8; ++j) rB[j] = p[(long)j * HID];
  };

  f32x4 acc[4][2];
  #pragma unroll
  for (int i = 0; i < 4; ++i)
    #pragma unroll
    for (int j = 0; j < 2; ++j) acc[i][j] = (f32x4)0.0f;

  LOAD_B(0);
  STAGE_A(0, 0);

  const int NIT = INTER / 32;   // 128
  for (int t = 0; t < NIT; ++t) {
    const int p = t & 1;
    {
      bf16x8 pk;
      #pragma unroll
      for (int j = 0; j < 8; ++j) pk[j] = (__bf16)rB[j];
      *(bf16x8*)&Bbf[p][(bk8 * 64 + bn) * 8] = pk;
    }
    if (t + 1 < NIT) LOAD_B(t + 1);
    __syncthreads();
    if (t + 1 < NIT) STAGE_A((t + 1) & 1, (long)(t + 1) * 32);
    const int k8 = lane >> 4;
    bf16x8 af[4], bf[2];
    #pragma unroll
    for (int f = 0; f < 4; ++f)
      af[f] = __builtin_bit_cast(bf16x8, *(const ushortx8*)&As[p][(wr * 64 + f * 16 + (lane & 15)) * 32 + k8 * 8]);
    #pragma unroll
    for (int j = 0; j < 2; ++j)
      bf[j] = __builtin_bit_cast(bf16x8, *(const ushortx8*)&Bbf[p][(k8 * 64 + wc * 32 + j * 16 + (lane & 15)) * 8]);
    #pragma unroll
    for (int i = 0; i < 4; ++i)
      #pragma unroll
      for (int j = 0; j < 2; ++j)
        acc[i][j] = __builtin_amdgcn_mfma_f32_16x16x32_bf16(af[i], bf[j], acc[i][j], 0, 0, 0);
  }

  const int rtop = off + cnt;
  const int grb  = off + mt * 128 + wr * 64;
  const int gcb  = nt * 64 + wc * 32;
  #pragma unroll
  for (int i = 0; i < 4; ++i) {
    #pragma unroll
    for (int j = 0; j < 2; ++j) {
      int gc = gcb + j * 16 + (lane & 15);
      #pragma unroll
      for (int q = 0; q < 4; ++q) {
        int gr = grb + i * 16 + (lane >> 4) * 4 + q;
        if (gr < rtop) {
          int a = rows[gr];
          y[(long)a * HID + gc] = acc[i][j][q];
        }
      }
    }
  }
}

// ---------------- combine: out[t] = ew0*Y[2t] + ew1*Y[2t+1] ----------------
__global__ void combine_kernel(const float* __restrict__ Y,
                               const float* __restrict__ ew,
                               float* __restrict__ out)
{
  int idx = blockIdx.x * 256 + threadIdx.x;
  int t = idx >> 9;
  int h = (idx & 511) * 4;
  float w0 = ew[2 * t], w1 = ew[2 * t + 1];
  float4 y0 = *(const float4*)&Y[(long)(2 * t) * HID + h];
  float4 y1 = *(const float4*)&Y[(long)(2 * t + 1) * HID + h];
  float4 o;
  o.x = w0 * y0.x + w1 * y1.x;
  o.y = w0 * y0.y + w1 * y1.y;
  o.z = w0 * y0.z + w1 * y1.z;
  o.w = w0 * y0.w + w1 * y1.w;
  *(float4*)&out[(long)t * HID + h] = o;
}

extern "C" void kernel_launch(void* const* d_in, const int* in_sizes, int n_in,
                              void* d_out, int out_size, void* d_ws, size_t ws_size,
                              hipStream_t stream) {
  const float* x   = (const float*)d_in[0];
  const int*   eix = (const int*)d_in[1];
  const float* ew  = (const float*)d_in[2];
  const float* w1  = (const float*)d_in[3];
  const float* w2  = (const float*)d_in[4];
  const float* w3  = (const float*)d_in[5];
  float* out = (float*)d_out;

  char* ws = (char*)d_ws;
  unsigned short* xb  = (unsigned short*)(ws + XB_OFF);
  unsigned short* gb  = (unsigned short*)(ws + GB_OFF);
  float*          y   = (float*)(ws + Y_OFF);
  int*            rows  = (int*)(ws + ROWS_OFF);
  int*            offs  = (int*)(ws + OFFS_OFF);
  int*            tiles = (int*)(ws + TILE_OFF);

  prep_kernel<<<4097, 256, 0, stream>>>(eix, x, xb, rows, offs, tiles);
  gemm_gateup<<<dim3(INTER / 64, NTSLOTS), 256, 0, stream>>>(
      xb, w1, w3, gb, rows, offs, tiles);
  gemm_down<<<dim3(HID / 64, NTSLOTS), 256, 0, stream>>>(
      gb, w2, y, rows, offs, tiles);
  combine_kernel<<<4096, 256, 0, stream>>>(y, ew, out);
}

// Round 19
// 455.604 us; speedup vs baseline: 1.8086x; 1.0552x over previous
//
#include <hip/hip_runtime.h>

#define EXPERTS 8
#define HID 2048
#define INTER 4096
#define BTOK 2048
#define NASSIGN 4096   // BTOK * TOPK
#define NTSLOTS 24     // BM=256: max sum_e ceil(cnt_e/256) = 16+8

typedef float f32x4 __attribute__((ext_vector_type(4)));
typedef __bf16 bf16x8 __attribute__((ext_vector_type(8)));
typedef unsigned short ushortx8 __attribute__((ext_vector_type(8)));

__device__ __forceinline__ unsigned short f2bf(float f) {
  union { float f; unsigned int u; } v; v.f = f;
  unsigned int r = v.u + 0x7fffu + ((v.u >> 16) & 1u);   // RNE
  return (unsigned short)(r >> 16);
}

// ---------------- workspace layout (bytes) ----------------
#define XB_OFF   0ULL                                   // [BTOK][HID] bf16 = 8 MiB
#define GB_OFF   (XB_OFF + 8388608ULL)                  // [NASSIGN][INTER] bf16 = 32 MiB
#define Y_OFF    (GB_OFF + 33554432ULL)                 // [NASSIGN][HID] f32 = 32 MiB
#define ROWS_OFF (Y_OFF  + 33554432ULL)                 // 4096 int
#define OFFS_OFF (ROWS_OFF + 16384ULL)                  // 9 int (padded 64B)
#define TILE_OFF (OFFS_OFF + 64ULL)                     // 24 int

// ---------------- prep: routing (block 0) + x f32->bf16 ----------------
__global__ void prep_kernel(const int* __restrict__ eraw,
                            const float* __restrict__ x,
                            unsigned short* __restrict__ xb,
                            int* __restrict__ rows, int* __restrict__ offs_g,
                            int* __restrict__ tiles)
{
  const int b = blockIdx.x;
  const int tid = threadIdx.x;

  if (b == 0) {
    __shared__ int cnt[256 * 8];
    __shared__ int offs_s[9];
    __shared__ int tot[8];
    __shared__ int found_odd;
    if (tid == 0) found_odd = 0;
    __syncthreads();
    int any = 0;
    for (int j = 0; j < 8; ++j) {
      int a = tid * 8 + j;
      any |= (eraw[2 * a + 1] != 0);
    }
    if (any) atomicOr(&found_odd, 1);
    __syncthreads();
    const bool i64 = (found_odd == 0);
    int lc[8];
    for (int e = 0; e < 8; ++e) lc[e] = 0;
    for (int j = 0; j < 16; ++j) {
      int a = tid * 16 + j;
      int e = i64 ? eraw[2 * a] : eraw[a];
      lc[e]++;
    }
    for (int e = 0; e < 8; ++e) cnt[tid * 8 + e] = lc[e];
    __syncthreads();
    if (tid < 8) {
      int run = 0;
      for (int t = 0; t < 256; ++t) {
        int v = cnt[t * 8 + tid];
        cnt[t * 8 + tid] = run;
        run += v;
      }
      tot[tid] = run;
    }
    __syncthreads();
    if (tid == 0) {
      int o = 0;
      for (int e = 0; e < 8; ++e) { offs_s[e] = o; o += tot[e]; }
      offs_s[8] = o;
      int s = 0;
      for (int e = 0; e < 8; ++e) {
        int nmt = (tot[e] + 255) >> 8;        // BM=256
        for (int m = 0; m < nmt; ++m) tiles[s++] = (e << 16) | m;
      }
      for (; s < NTSLOTS; ++s) tiles[s] = -1;
    }
    __syncthreads();
    if (tid < 9) offs_g[tid] = offs_s[tid];
    int lc2[8];
    for (int e = 0; e < 8; ++e) lc2[e] = 0;
    for (int j = 0; j < 16; ++j) {
      int a = tid * 16 + j;
      int e = i64 ? eraw[2 * a] : eraw[a];
      rows[offs_s[e] + cnt[tid * 8 + e] + lc2[e]] = a;
      lc2[e]++;
    }
  } else {
    long idx = (long)(b - 1) * 256 + tid;
    float4 v = *(const float4*)&x[idx * 4];
    unsigned int lo = (unsigned int)f2bf(v.x) | ((unsigned int)f2bf(v.y) << 16);
    unsigned int hi = (unsigned int)f2bf(v.z) | ((unsigned int)f2bf(v.w) << 16);
    uint2 p; p.x = lo; p.y = hi;
    *(uint2*)&xb[idx * 4] = p;
  }
}

// ---------------- gate+up grouped GEMM: BM=256, 512 threads, 8 waves --------
// R18-proven single-barrier schedule, scaled: thread halves split B1/B3
// reg-staging (8 loads + 1 ds_write each). LDS 48 KiB -> 3 blocks/CU
// (24 waves/CU, 2x R18's TLP); weight re-reads halved (2 M-passes).
__global__ __launch_bounds__(512, 4) void gemm_gateup(
    const unsigned short* __restrict__ xb,
    const float* __restrict__ w1,
    const float* __restrict__ w3,
    unsigned short* __restrict__ gb,
    const int* __restrict__ rows,
    const int* __restrict__ offs,
    const int* __restrict__ tiles)
{
  const int te = tiles[blockIdx.y];
  if (te < 0) return;
  const int e  = te >> 16, mt = te & 0xffff;
  const int off = offs[e];
  const int cnt = offs[e + 1] - off;
  const int nt  = blockIdx.x;                 // 64 N-tiles of 64 over INTER

  __shared__ __align__(16) unsigned short As[2][256 * 32];    // 32 KiB
  __shared__ __align__(16) unsigned short B1bf[2][4 * 64 * 8];//  8 KiB
  __shared__ __align__(16) unsigned short B3bf[2][4 * 64 * 8];//  8 KiB

  const int tid  = threadIdx.x;
  const int lane = tid & 63;
  const int wave = tid >> 6;                  // 8 waves
  const int wr = wave >> 1, wc = wave & 1;    // wr: 4x64 rows, wc: 2x32 cols

  // A staging: 1024 slots (256 rows x 4 segs) over 512 threads x 2 chunks
  const unsigned short* aptr[2];
  #pragma unroll
  for (int c = 0; c < 2; ++c) {
    int idx = tid + c * 512;
    int row = idx >> 2, seg = idx & 3;
    int rr = off + mt * 256 + row;
    int rv = (rr < off + cnt) ? rr : (off + cnt - 1);
    long tok = rows[rv] >> 1;
    aptr[c] = xb + tok * HID + seg * 8;
  }
  // B reg-staging: tid<256 -> B1, tid>=256 -> B3; slot = tid&255
  const int bslot = tid & 255;
  const int bn = bslot & 63, bk8 = bslot >> 6;   // bk8 in 0..3
  const bool isB1 = (tid < 256);
  const float* wsel = isB1 ? w1 : w3;
  const float* bbase = wsel + ((long)e * HID + bk8 * 8) * INTER + nt * 64 + bn;

  auto STAGE_A = [&](int abuf, long k32) {
    #pragma unroll
    for (int c = 0; c < 2; ++c)
      __builtin_amdgcn_global_load_lds(
          (const __attribute__((address_space(1))) unsigned int*)(aptr[c] + k32),
          (__attribute__((address_space(3))) unsigned int*)(&As[abuf][(tid + c * 512) * 8]),
          16, 0, 0);
  };

  float rB[8];
  auto LOAD_B = [&](int t) {
    const float* p = bbase + (long)t * 32 * INTER;
    #pragma unroll
    for (int j = 0; j < 8; ++j) rB[j] = p[(long)j * INTER];
  };

  f32x4 acc1[4][2], acc3[4][2];
  #pragma unroll
  for (int i = 0; i < 4; ++i)
    #pragma unroll
    for (int j = 0; j < 2; ++j) { acc1[i][j] = (f32x4)0.0f; acc3[i][j] = (f32x4)0.0f; }

  LOAD_B(0);
  STAGE_A(0, 0);

  const int NIT = HID / 32;   // 64
  for (int t = 0; t < NIT; ++t) {
    const int p = t & 1;
    // convert B(t) from regs -> Bbf[p] (one b128 write, banks bn*4: min alias)
    {
      bf16x8 pk;
      #pragma unroll
      for (int j = 0; j < 8; ++j) pk[j] = (__bf16)rB[j];
      if (isB1) *(bf16x8*)&B1bf[p][(bk8 * 64 + bn) * 8] = pk;
      else      *(bf16x8*)&B3bf[p][(bk8 * 64 + bn) * 8] = pk;
    }
    if (t + 1 < NIT) LOAD_B(t + 1);          // spans the barrier (VGPR loads)
    __syncthreads();                         // publish Bbf(t); drain As(t)
    if (t + 1 < NIT) STAGE_A((t + 1) & 1, (long)(t + 1) * 32);
    const int k8 = lane >> 4;
    bf16x8 af[4], b1f[2], b3f[2];
    #pragma unroll
    for (int f = 0; f < 4; ++f)
      af[f] = __builtin_bit_cast(bf16x8, *(const ushortx8*)&As[p][(wr * 64 + f * 16 + (lane & 15)) * 32 + k8 * 8]);
    #pragma unroll
    for (int j = 0; j < 2; ++j) {
      b1f[j] = __builtin_bit_cast(bf16x8, *(const ushortx8*)&B1bf[p][(k8 * 64 + wc * 32 + j * 16 + (lane & 15)) * 8]);
      b3f[j] = __builtin_bit_cast(bf16x8, *(const ushortx8*)&B3bf[p][(k8 * 64 + wc * 32 + j * 16 + (lane & 15)) * 8]);
    }
    #pragma unroll
    for (int i = 0; i < 4; ++i)
      #pragma unroll
      for (int j = 0; j < 2; ++j) {
        acc1[i][j] = __builtin_amdgcn_mfma_f32_16x16x32_bf16(af[i], b1f[j], acc1[i][j], 0, 0, 0);
        acc3[i][j] = __builtin_amdgcn_mfma_f32_16x16x32_bf16(af[i], b3f[j], acc3[i][j], 0, 0, 0);
      }
  }

  const int rtop = off + cnt;
  const int grb  = off + mt * 256 + wr * 64;
  const int gcb  = nt * 64 + wc * 32;
  #pragma unroll
  for (int i = 0; i < 4; ++i) {
    #pragma unroll
    for (int j = 0; j < 2; ++j) {
      int gc = gcb + j * 16 + (lane & 15);
      #pragma unroll
      for (int qq = 0; qq < 4; ++qq) {
        int gr = grb + i * 16 + (lane >> 4) * 4 + qq;
        if (gr < rtop) {
          float g = acc1[i][j][qq];
          float u = acc3[i][j][qq];
          float s = g / (1.0f + __expf(-g));
          gb[(long)gr * INTER + gc] = f2bf(s * u);
        }
      }
    }
  }
}

// ---------------- down grouped GEMM: BM=256, 512 threads, 8 waves -----------
// LDS 40 KiB -> 4 blocks/CU = 32 waves/CU. B staged by tid<256 only.
__global__ __launch_bounds__(512, 4) void gemm_down(
    const unsigned short* __restrict__ gbin,
    const float* __restrict__ w2,
    float* __restrict__ y,
    const int* __restrict__ rows,
    const int* __restrict__ offs,
    const int* __restrict__ tiles)
{
  const int te = tiles[blockIdx.y];
  if (te < 0) return;
  const int e  = te >> 16, mt = te & 0xffff;
  const int off = offs[e];
  const int cnt = offs[e + 1] - off;
  const int nt  = blockIdx.x;                 // 32 N-tiles of 64 over HID

  __shared__ __align__(16) unsigned short As[2][256 * 32];    // 32 KiB
  __shared__ __align__(16) unsigned short Bbf[2][4 * 64 * 8]; //  8 KiB

  const int tid  = threadIdx.x;
  const int lane = tid & 63;
  const int wave = tid >> 6;
  const int wr = wave >> 1, wc = wave & 1;

  const unsigned short* aptr[2];
  #pragma unroll
  for (int c = 0; c < 2; ++c) {
    int idx = tid + c * 512;
    int row = idx >> 2, seg = idx & 3;
    int rr = off + mt * 256 + row;
    int rv = (rr < off + cnt) ? rr : (off + cnt - 1);
    aptr[c] = gbin + (long)rv * INTER + seg * 8;
  }
  const int bslot = tid & 255;
  const int bn = bslot & 63, bk8 = bslot >> 6;
  const bool doB = (tid < 256);
  const float* bbase = w2 + ((long)e * INTER + bk8 * 8) * HID + nt * 64 + bn;

  auto STAGE_A = [&](int abuf, long k32) {
    #pragma unroll
    for (int c = 0; c < 2; ++c)
      __builtin_amdgcn_global_load_lds(
          (const __attribute__((address_space(1))) unsigned int*)(aptr[c] + k32),
          (__attribute__((address_space(3))) unsigned int*)(&As[abuf][(tid + c * 512) * 8]),
          16, 0, 0);
  };

  float rB[8];
  auto LOAD_B = [&](int t) {
    if (doB) {
      const float* p = bbase + (long)t * 32 * HID;
      #pragma unroll
      for (int j = 0; j < 8; ++j) rB[j] = p[(long)j * HID];
    }
  };

  f32x4 acc[4][2];
  #pragma unroll
  for (int i = 0; i < 4; ++i)
    #pragma unroll
    for (int j = 0; j < 2; ++j) acc[i][j] = (f32x4)0.0f;

  LOAD_B(0);
  STAGE_A(0, 0);

  const int NIT = INTER / 32;   // 128
  for (int t = 0; t < NIT; ++t) {
    const int p = t & 1;
    if (doB) {
      bf16x8 pk;
      #pragma unroll
      for (int j = 0; j < 8; ++j) pk[j] = (__bf16)rB[j];
      *(bf16x8*)&Bbf[p][(bk8 * 64 + bn) * 8] = pk;
    }
    if (t + 1 < NIT) LOAD_B(t + 1);
    __syncthreads();
    if (t + 1 < NIT) STAGE_A((t + 1) & 1, (long)(t + 1) * 32);
    const int k8 = lane >> 4;
    bf16x8 af[4], bf[2];
    #pragma unroll
    for (int f = 0; f < 4; ++f)
      af[f] = __builtin_bit_cast(bf16x8, *(const ushortx8*)&As[p][(wr * 64 + f * 16 + (lane & 15)) * 32 + k8 * 8]);
    #pragma unroll
    for (int j = 0; j < 2; ++j)
      bf[j] = __builtin_bit_cast(bf16x8, *(const ushortx8*)&Bbf[p][(k8 * 64 + wc * 32 + j * 16 + (lane & 15)) * 8]);
    #pragma unroll
    for (int i = 0; i < 4; ++i)
      #pragma unroll
      for (int j = 0; j < 2; ++j)
        acc[i][j] = __builtin_amdgcn_mfma_f32_16x16x32_bf16(af[i], bf[j], acc[i][j], 0, 0, 0);
  }

  const int rtop = off + cnt;
  const int grb  = off + mt * 256 + wr * 64;
  const int gcb  = nt * 64 + wc * 32;
  #pragma unroll
  for (int i = 0; i < 4; ++i) {
    #pragma unroll
    for (int j = 0; j < 2; ++j) {
      int gc = gcb + j * 16 + (lane & 15);
      #pragma unroll
      for (int q = 0; q < 4; ++q) {
        int gr = grb + i * 16 + (lane >> 4) * 4 + q;
        if (gr < rtop) {
          int a = rows[gr];
          y[(long)a * HID + gc] = acc[i][j][q];
        }
      }
    }
  }
}

// ---------------- combine: out[t] = ew0*Y[2t] + ew1*Y[2t+1] ----------------
__global__ void combine_kernel(const float* __restrict__ Y,
                               const float* __restrict__ ew,
                               float* __restrict__ out)
{
  int idx = blockIdx.x * 256 + threadIdx.x;
  int t = idx >> 9;
  int h = (idx & 511) * 4;
  float w0 = ew[2 * t], w1 = ew[2 * t + 1];
  float4 y0 = *(const float4*)&Y[(long)(2 * t) * HID + h];
  float4 y1 = *(const float4*)&Y[(long)(2 * t + 1) * HID + h];
  float4 o;
  o.x = w0 * y0.x + w1 * y1.x;
  o.y = w0 * y0.y + w1 * y1.y;
  o.z = w0 * y0.z + w1 * y1.z;
  o.w = w0 * y0.w + w1 * y1.w;
  *(float4*)&out[(long)t * HID + h] = o;
}

extern "C" void kernel_launch(void* const* d_in, const int* in_sizes, int n_in,
                              void* d_out, int out_size, void* d_ws, size_t ws_size,
                              hipStream_t stream) {
  const float* x   = (const float*)d_in[0];
  const int*   eix = (const int*)d_in[1];
  const float* ew  = (const float*)d_in[2];
  const float* w1  = (const float*)d_in[3];
  const float* w2  = (const float*)d_in[4];
  const float* w3  = (const float*)d_in[5];
  float* out = (float*)d_out;

  char* ws = (char*)d_ws;
  unsigned short* xb  = (unsigned short*)(ws + XB_OFF);
  unsigned short* gb  = (unsigned short*)(ws + GB_OFF);
  float*          y   = (float*)(ws + Y_OFF);
  int*            rows  = (int*)(ws + ROWS_OFF);
  int*            offs  = (int*)(ws + OFFS_OFF);
  int*            tiles = (int*)(ws + TILE_OFF);

  prep_kernel<<<4097, 256, 0, stream>>>(eix, x, xb, rows, offs, tiles);
  gemm_gateup<<<dim3(INTER / 64, NTSLOTS), 512, 0, stream>>>(
      xb, w1, w3, gb, rows, offs, tiles);
  gemm_down<<<dim3(HID / 64, NTSLOTS), 512, 0, stream>>>(
      gb, w2, y, rows, offs, tiles);
  combine_kernel<<<4096, 256, 0, stream>>>(y, ew, out);
}